// Round 4
// baseline (1340.901 us; speedup 1.0000x reference)
//
#include <hip/hip_runtime.h>
#include <math.h>

#define T_DIM 1024
#define B_DIM 128
#define L_DIM 128

using bf16x8 = __attribute__((ext_vector_type(8))) __bf16;
using f32x16 = __attribute__((ext_vector_type(16))) float;
using v4i    = __attribute__((ext_vector_type(4))) int;
using f4     = __attribute__((ext_vector_type(4))) float;

__device__ __forceinline__ int cvtpk_bf16(float lo, float hi) {
    int r;
    asm("v_cvt_pk_bf16_f32 %0, %1, %2" : "=v"(r) : "v"(lo), "v"(hi));
    return r;
}

// after call: a = [a.lanes<32 | b.lanes<32], b = [a.lanes>=32 | b.lanes>=32]
__device__ __forceinline__ void plswap(int &a, int &b) {
    auto r = __builtin_amdgcn_permlane32_swap(a, b, false, false);
    a = r[0];
    b = r[1];
}

__device__ __forceinline__ float readlane0_f32(float v) {
    return __uint_as_float(__builtin_amdgcn_readfirstlane(__float_as_uint(v)));
}

// ---------------------------------------------------------------------------
// Pre-kernel: ep[t][g][lane][64] = exp(pred) packed in the den wave's C-reg
// order (rowbase = 32*rt + 8*q + 4*hi, elem 0..3), plus padded mask copy.
// ---------------------------------------------------------------------------
__global__ __launch_bounds__(256)
void crf_prep(const float* __restrict__ pred, const int* __restrict__ mask,
              float* __restrict__ ep, int* __restrict__ mkp)
{
    const int gid = blockIdx.x * 256 + threadIdx.x;
#pragma unroll
    for (int s = 0; s < 2; ++s) {
        const int idx4 = gid * 2 + s;            // < 4,194,304
        const int k4 = idx4 & 15;
        const int l  = (idx4 >> 4) & 63;
        const int g  = (idx4 >> 10) & 3;
        const int t  = idx4 >> 12;               // < 1024
        const int c  = l & 31, hh = l >> 5;
        const int bb = g * 32 + c;
        const int rt = k4 >> 2, q = k4 & 3;
        const int rowbase = 32 * rt + 8 * q + 4 * hh;
        const f4 p = *(const f4*)&pred[((size_t)t * B_DIM + bb) * L_DIM + rowbase];
        f4 e;
        e[0] = __expf(p[0]); e[1] = __expf(p[1]);
        e[2] = __expf(p[2]); e[3] = __expf(p[3]);
        *(f4*)&ep[(size_t)idx4 * 4] = e;
    }
    if (gid < 1026 * B_DIM) {
        const int t = gid >> 7;
        const int cc = gid & 127;
        mkp[gid] = mask[(t < T_DIM ? t : T_DIM - 1) * B_DIM + cc];
    }
}

// ---------------------------------------------------------------------------
// One forward step. 32 MFMA + in-register relayout. No LDS, no barriers.
// ---------------------------------------------------------------------------
template <int RN>
__device__ __forceinline__ void den_step(
    const bf16x8 (&Afr)[4][8], v4i (&Bw)[8], const f32x16 &Zf,
    f4 (&EX)[16], int &MKX, const f4*& EPP, const int*& MPP, int &Dc)
{
    const bool mkb = (MKX != 0);

    // D = E^T @ U  (ks-inner so each tile's chain finishes early)
    f32x16 dd[4];
#pragma unroll
    for (int rt = 0; rt < 4; ++rt) {
        f32x16 a = __builtin_amdgcn_mfma_f32_32x32x16_bf16(
            Afr[rt][0], __builtin_bit_cast(bf16x8, Bw[0]), Zf, 0, 0, 0);
#pragma unroll
        for (int ks = 1; ks < 8; ++ks)
            a = __builtin_amdgcn_mfma_f32_32x32x16_bf16(
                Afr[rt][ks], __builtin_bit_cast(bf16x8, Bw[ks]), a, 0, 0, 0);
        dd[rt] = a;
    }

    // U' = D * ep   (ep prefetched 2 steps ago)
#pragma unroll
    for (int rt = 0; rt < 4; ++rt)
#pragma unroll
        for (int reg = 0; reg < 16; ++reg)
            dd[rt][reg] *= EX[rt * 4 + (reg >> 2)][reg & 3];

    // issue prefetch for t+2 NOW (in-flight across the rest of this step,
    // the whole of step t+1, and step t+2's MFMA phase -> covers HBM latency)
#pragma unroll
    for (int i = 0; i < 16; ++i) EX[i] = EPP[i];
    EPP += 8192;                         // 2 * 16384 floats = 8192 float4
    const int mknew = *MPP; MPP += 2 * B_DIM;

    if (RN) {   // lazy per-column power-of-2 renorm (every 4 steps)
        float mx = 0.f;
#pragma unroll
        for (int rt = 0; rt < 4; ++rt)
#pragma unroll
            for (int reg = 0; reg < 16; ++reg)
                mx = fmaxf(mx, __builtin_fabsf(dd[rt][reg]));
        mx = fmaxf(mx, __shfl_xor(mx, 32, 64));
        const int eb = (int)((__float_as_uint(mx) >> 23) & 255);
        const float sc = __uint_as_float((unsigned)(254 - eb) << 23);
#pragma unroll
        for (int rt = 0; rt < 4; ++rt)
#pragma unroll
            for (int reg = 0; reg < 16; ++reg)
                dd[rt][reg] *= sc;
        if (mkb) Dc += eb - 127;        // per-column scale bookkeeping
    }

    // relayout C -> B fragments: cvt_pk + permlane32_swap, masked select
#pragma unroll
    for (int rt = 0; rt < 4; ++rt) {
        int w0 = cvtpk_bf16(dd[rt][0],  dd[rt][1]);
        int w1 = cvtpk_bf16(dd[rt][2],  dd[rt][3]);
        int w2 = cvtpk_bf16(dd[rt][4],  dd[rt][5]);
        int w3 = cvtpk_bf16(dd[rt][6],  dd[rt][7]);
        int w4 = cvtpk_bf16(dd[rt][8],  dd[rt][9]);
        int w5 = cvtpk_bf16(dd[rt][10], dd[rt][11]);
        int w6 = cvtpk_bf16(dd[rt][12], dd[rt][13]);
        int w7 = cvtpk_bf16(dd[rt][14], dd[rt][15]);
        plswap(w0, w2); plswap(w1, w3);
        plswap(w4, w6); plswap(w5, w7);
        Bw[2*rt][0]   = mkb ? w0 : Bw[2*rt][0];
        Bw[2*rt][1]   = mkb ? w1 : Bw[2*rt][1];
        Bw[2*rt][2]   = mkb ? w2 : Bw[2*rt][2];
        Bw[2*rt][3]   = mkb ? w3 : Bw[2*rt][3];
        Bw[2*rt+1][0] = mkb ? w4 : Bw[2*rt+1][0];
        Bw[2*rt+1][1] = mkb ? w5 : Bw[2*rt+1][1];
        Bw[2*rt+1][2] = mkb ? w6 : Bw[2*rt+1][2];
        Bw[2*rt+1][3] = mkb ? w7 : Bw[2*rt+1][3];
    }
    MKX = mknew;
}

// ---------------------------------------------------------------------------
// Denominator: 4 blocks x 1 wave; block g owns batch columns [32g, 32g+32).
// score represented as u (bf16 B-fragments) * 2^Dc per column.
// ---------------------------------------------------------------------------
__global__ __launch_bounds__(64, 1)
void crf_den_mfma(const float* __restrict__ pred,
                  const float* __restrict__ trans,
                  const float* __restrict__ start_s,
                  const float* __restrict__ end_s,
                  const float* __restrict__ ep,
                  const int*   __restrict__ mkp,
                  float* __restrict__ den_out)
{
    const int g    = blockIdx.x;
    const int lane = threadIdx.x;
    const int c    = lane & 31;
    const int hi   = lane >> 5;
    const int b    = g * 32 + c;

    // A fragments (permanent): A[m][k] = exp(trans[k][m]),
    // m = 32rt + (lane&31), k = 16ks + 8*(lane>>5) + r
    bf16x8 Afr[4][8];
#pragma unroll
    for (int rt = 0; rt < 4; ++rt)
#pragma unroll
        for (int ks = 0; ks < 8; ++ks)
#pragma unroll
            for (int r = 0; r < 8; ++r) {
                const int kg = 16 * ks + 8 * hi + r;
                const int m  = 32 * rt + c;
                Afr[rt][ks][r] = (__bf16)__expf(trans[kg * L_DIM + m]);
            }

    // B fragments at t=0: u0 = exp(start + pred[0])
    v4i Bw[8];
#pragma unroll
    for (int ks = 0; ks < 8; ++ks)
#pragma unroll
        for (int w = 0; w < 4; ++w) {
            const int k0 = 16 * ks + 8 * hi + 2 * w;
            const float u0 = __expf(start_s[k0]     + pred[(size_t)b * L_DIM + k0]);
            const float u1 = __expf(start_s[k0 + 1] + pred[(size_t)b * L_DIM + k0 + 1]);
            Bw[ks][w] = cvtpk_bf16(u0, u1);
        }

    f32x16 Zf;
#pragma unroll
    for (int k = 0; k < 16; ++k) Zf[k] = 0.0f;

    // ep / mask prefetch pipeline (2-deep, parity A=odd t, B=even t)
    const f4* epA = (const f4*)(ep + (size_t)1 * 16384 + g * 4096 + lane * 64);
    const f4* epB = (const f4*)(ep + (size_t)2 * 16384 + g * 4096 + lane * 64);
    f4 EA[16], EB[16];
#pragma unroll
    for (int i = 0; i < 16; ++i) EA[i] = epA[i];
    epA += 8192;
#pragma unroll
    for (int i = 0; i < 16; ++i) EB[i] = epB[i];
    epB += 8192;
    const int* mpA = mkp + 1 * B_DIM + b;
    const int* mpB = mkp + 2 * B_DIM + b;
    int mkA = *mpA; mpA += 2 * B_DIM;
    int mkB = *mpB; mpB += 2 * B_DIM;
    int Dc = 0;

    // steps t = 1..1023; renorm at t % 4 == 0
#pragma unroll 1
    for (int it = 0; it < 255; ++it) {
        den_step<0>(Afr, Bw, Zf, EA, mkA, epA, mpA, Dc);
        den_step<0>(Afr, Bw, Zf, EB, mkB, epB, mpB, Dc);
        den_step<0>(Afr, Bw, Zf, EA, mkA, epA, mpA, Dc);
        den_step<1>(Afr, Bw, Zf, EB, mkB, epB, mpB, Dc);
    }
    den_step<0>(Afr, Bw, Zf, EA, mkA, epA, mpA, Dc);   // t = 1021
    den_step<0>(Afr, Bw, Zf, EB, mkB, epB, mpB, Dc);   // t = 1022
    den_step<0>(Afr, Bw, Zf, EA, mkA, epA, mpA, Dc);   // t = 1023

    // final: den[b] = log( sum_state u[state] * exp(end[state]) ) + Dc*ln2
    float csum = 0.f;
#pragma unroll
    for (int ks = 0; ks < 8; ++ks)
#pragma unroll
        for (int w = 0; w < 4; ++w) {
            const int dw = Bw[ks][w];
            const int k0 = 16 * ks + 8 * hi + 2 * w;
            const float lo = __uint_as_float(((unsigned)dw & 0xffffu) << 16);
            const float hh = __uint_as_float((unsigned)dw & 0xffff0000u);
            csum += lo * __expf(end_s[k0]);
            csum += hh * __expf(end_s[k0 + 1]);
        }
    csum += __shfl_xor(csum, 32, 64);
    if (hi == 0)
        den_out[b] = logf(csum) + (float)Dc * 0.69314718055994531f;
}

// ---------------------------------------------------------------------------
// R3 fallback denominator (used only if ws too small for the ep buffer)
// ---------------------------------------------------------------------------
__global__ __launch_bounds__(512, 1)
void crf_den_kernel(const float* __restrict__ pred,
                    const int*   __restrict__ mask,
                    const float* __restrict__ trans,
                    const float* __restrict__ start_s,
                    const float* __restrict__ end_s,
                    float* __restrict__ den_out)
{
    const int b     = blockIdx.x;
    const int tid   = threadIdx.x;
    const int w     = tid >> 6;
    const int lane  = tid & 63;
    const int sub   = lane & 15;
    const int kq    = lane >> 4;
    const int state = w * 16 + sub;
    const int kbase = kq * 32;

    float etr[32];
#pragma unroll
    for (int ii = 0; ii < 32; ++ii)
        etr[ii] = __expf(trans[(kbase + ii) * L_DIM + state]);

    __shared__ __align__(16) float es_lds[2][4 * 132];
    __shared__ __align__(16) int   e_lds[2][8];
    __shared__ float fsum_lds[8];

    float u = __expf(start_s[state] + pred[b * L_DIM + state]);
    int   D = 0;

    float ep_next = __expf(pred[(1 * B_DIM + b) * L_DIM + state]);
    float p2      = pred[(2 * B_DIM + b) * L_DIM + state];
    int   mk_next = mask[1 * B_DIM + b];
    int   mk2     = mask[2 * B_DIM + b];

    for (int t = 1; t < T_DIM; ++t) {
        const float ep_cur = ep_next;
        const int   mk     = mk_next;
        const int tpre = (t + 2 < T_DIM) ? (t + 2) : (T_DIM - 1);
        const float p3  = pred[(tpre * B_DIM + b) * L_DIM + state];
        const int   mk3 = mask[tpre * B_DIM + b];
        ep_next = __expf(p2);
        p2 = p3; mk_next = mk2; mk2 = mk3;

        const int buf = t & 1;
        const unsigned ub      = __float_as_uint(readlane0_f32(u));
        const int      Ebiased = (int)(ub >> 23);
        const float    scale   = __uint_as_float((unsigned)(254 - Ebiased) << 23);
        const float    us      = u * scale;
        if (lane < 16) {
            float* dst = &es_lds[buf][state];
#pragma unroll
            for (int cc = 0; cc < 4; ++cc) dst[cc * 132] = us;
        }
        if (lane == 0) e_lds[buf][w] = Ebiased;

        asm volatile("s_waitcnt lgkmcnt(0)" ::: "memory");
        __builtin_amdgcn_s_barrier();
        __builtin_amdgcn_sched_barrier(0);

        const float* esb = &es_lds[buf][kq * 132 + kbase];
        const v4i  eL = *(const v4i*)&e_lds[buf][0];
        const v4i  eH = *(const v4i*)&e_lds[buf][4];

        float accA = 0.f, accB = 0.f;
#pragma unroll
        for (int cc = 0; cc < 4; ++cc) {
            const f4 e4 = *(const f4*)&esb[cc * 4];
            accA = fmaf(e4[0], etr[cc*4+0], accA);
            accA = fmaf(e4[1], etr[cc*4+1], accA);
            accA = fmaf(e4[2], etr[cc*4+2], accA);
            accA = fmaf(e4[3], etr[cc*4+3], accA);
        }
#pragma unroll
        for (int cc = 4; cc < 8; ++cc) {
            const f4 e4 = *(const f4*)&esb[cc * 4];
            accB = fmaf(e4[0], etr[cc*4+0], accB);
            accB = fmaf(e4[1], etr[cc*4+1], accB);
            accB = fmaf(e4[2], etr[cc*4+2], accB);
            accB = fmaf(e4[3], etr[cc*4+3], accB);
        }

        const int emax = max(max(max(eL[0], eL[1]), max(eL[2], eL[3])),
                             max(max(eH[0], eH[1]), max(eH[2], eH[3])));
        int eA, eB;
        switch (kq) {
            case 0: eA = eL[0]; eB = eL[1]; break;
            case 1: eA = eL[2]; eB = eL[3]; break;
            case 2: eA = eH[0]; eB = eH[1]; break;
            default: eA = eH[2]; eB = eH[3]; break;
        }
        float part = ldexpf(accA, eA - emax) + ldexpf(accB, eB - emax);
        part += __shfl_xor(part, 16, 64);
        part += __shfl_xor(part, 32, 64);

        if (mk) { u = part * ep_cur; D += (emax - 127); }
    }

    float val = (kq == 0) ? u * __expf(end_s[state]) : 0.f;
#pragma unroll
    for (int off = 32; off >= 1; off >>= 1)
        val += __shfl_xor(val, off, 64);
    if (lane == 0) fsum_lds[w] = val;
    __syncthreads();
    if (tid == 0) {
        float tot = 0.f;
#pragma unroll
        for (int ww = 0; ww < 8; ++ww) tot += fsum_lds[ww];
        den_out[b] = logf(tot) + (float)D * 0.69314718055994531f;
    }
}

// ---------------------------------------------------------------------------
// Numerator
// ---------------------------------------------------------------------------
__global__ __launch_bounds__(256, 1)
void crf_num_kernel(const float* __restrict__ pred,
                    const int*   __restrict__ targets,
                    const int*   __restrict__ mask,
                    const float* __restrict__ trans,
                    const float* __restrict__ start_s,
                    const float* __restrict__ end_s,
                    float* __restrict__ num_out)
{
    const int b = blockIdx.x;
    const int k = threadIdx.x;

    float local = 0.f;
    int   msum  = 0;
    for (int t = k; t < T_DIM; t += 256) {
        const int mk = mask[t * B_DIM + b];
        msum += mk;
        if (t >= 1) {
            const int tp = targets[(t - 1) * B_DIM + b];
            const int tc = targets[t * B_DIM + b];
            const float cc = trans[tp * L_DIM + tc] +
                             pred[((size_t)t * B_DIM + b) * L_DIM + tc];
            local += cc * (float)mk;
        }
    }

#pragma unroll
    for (int off = 32; off >= 1; off >>= 1) {
        local += __shfl_xor(local, off, 64);
        msum  += __shfl_xor(msum,  off, 64);
    }
    __shared__ float sred[4];
    __shared__ int   ired[4];
    const int w = k >> 6;
    if ((k & 63) == 0) { sred[w] = local; ired[w] = msum; }
    __syncthreads();
    if (k == 0) {
        float tot = sred[0] + sred[1] + sred[2] + sred[3];
        const int ms = ired[0] + ired[1] + ired[2] + ired[3];
        const int t0 = targets[b];
        tot += start_s[t0] + pred[(size_t)b * L_DIM + t0];
        const int last = ms - 1;
        tot += end_s[targets[last * B_DIM + b]];
        num_out[b] = tot;
    }
}

__global__ __launch_bounds__(128, 1)
void crf_reduce_kernel(const float* __restrict__ den,
                       const float* __restrict__ num,
                       float* __restrict__ out)
{
    const int j = threadIdx.x;
    float d = den[j] - num[j];
#pragma unroll
    for (int off = 32; off >= 1; off >>= 1)
        d += __shfl_xor(d, off, 64);
    __shared__ float s[2];
    if ((j & 63) == 0) s[j >> 6] = d;
    __syncthreads();
    if (j == 0) out[0] = (s[0] + s[1]) * (1.0f / (float)B_DIM);
}

extern "C" void kernel_launch(void* const* d_in, const int* in_sizes, int n_in,
                              void* d_out, int out_size, void* d_ws, size_t ws_size,
                              hipStream_t stream)
{
    const float* pred    = (const float*)d_in[0];
    const int*   targets = (const int*)  d_in[1];
    const int*   mask    = (const int*)  d_in[2];
    const float* trans   = (const float*)d_in[3];
    const float* start_s = (const float*)d_in[4];
    const float* end_s   = (const float*)d_in[5];
    float* out = (float*)d_out;

    const size_t EPF  = (size_t)1026 * 16384;   // padded ep floats
    const size_t MPI  = (size_t)1026 * 128;     // padded mask ints
    const size_t NEED = (EPF + MPI + 256) * sizeof(float);

    if (ws_size >= NEED) {
        float* ep  = (float*)d_ws;
        int*   mkp = (int*)(ep + EPF);
        float* den = (float*)(mkp + MPI);
        float* num = den + B_DIM;
        crf_prep<<<8192, 256, 0, stream>>>(pred, mask, ep, mkp);
        crf_num_kernel<<<B_DIM, 256, 0, stream>>>(pred, targets, mask, trans,
                                                  start_s, end_s, num);
        crf_den_mfma<<<4, 64, 0, stream>>>(pred, trans, start_s, end_s,
                                           ep, mkp, den);
        crf_reduce_kernel<<<1, 128, 0, stream>>>(den, num, out);
    } else {
        float* den = (float*)d_ws;
        float* num = den + B_DIM;
        crf_den_kernel<<<B_DIM, 512, 0, stream>>>(pred, mask, trans,
                                                  start_s, end_s, den);
        crf_num_kernel<<<B_DIM, 256, 0, stream>>>(pred, targets, mask, trans,
                                                  start_s, end_s, num);
        crf_reduce_kernel<<<1, 128, 0, stream>>>(den, num, out);
    }
}